// Round 3
// baseline (10087.091 us; speedup 1.0000x reference)
//
#include <hip/hip_runtime.h>
#include <stdint.h>

// SpikingNetwork B=128 T=128 I=1024 dims 2048/2048/1024, beta=0.9, thr=1.0.
// R7: R5 structure (proven 7.6ms: 64m x 32n tiles, 4m x 2n/thread, L0 self-
// contained K=1024, L1/L2 ksplit2, same flags/partials/LIF) + latency-hiding
// chunk pipeline: chunk K=64, LDS double-buffer, ONE raw barrier per chunk
// (lgkmcnt(0)+s_barrier, NO vmcnt drain), next chunk's global loads prefetched
// into regs during current FMA phase (hidden under 1024-cy FMA window).
// DAG bit-identical to R5: per-output sequential fmac over each 512-k chain,
// ascending chunks; owner merges ((P0+P1)+P2)+P3 with __fadd_rn.

#define TT   128
#define NB   128
#define DD2  1024

// ws layout (u32 units) — identical to R5
#define SPK0_OFF 0u
#define SPK1_OFF (128u*128u*64u)                 // 1,048,576
#define PART_OFF (2u*128u*128u*64u)              // 2,097,152
#define NHELP    192u
#define FLG_OFF  (PART_OFF + NHELP*4096u)        // 2,883,584
#define NFLG     1536u                           // pflag512 oflag512 done0 2x128 done1 2x128
#define WS_NEED_BYTES ((size_t)(FLG_OFF + NFLG) * 4u)   // 11,540,480

__device__ __forceinline__ void wait_ge(uint32_t* p, uint32_t tgt){
  while (__hip_atomic_load(p, __ATOMIC_ACQUIRE, __HIP_MEMORY_SCOPE_AGENT) < tgt)
    __builtin_amdgcn_s_sleep(1);
}

// LDS column swizzle for lA: 4-float granules (b128-aligned); constant over a
// 4-aligned k-granule. Spreads both staging-store and fma-read banks.
__device__ __forceinline__ int fswz(int k){
  return (k & 16) | ((k ^ (k >> 3)) & 12);
}

__global__ void sentinel_kernel(float* o){ o[0] = 42.0f; }   // ws-too-small marker

__global__ __launch_bounds__(256, 2) void snn_kernel(
    const float* __restrict__ x,
    const float* __restrict__ W0, const float* __restrict__ b0,
    const float* __restrict__ W1, const float* __restrict__ b1,
    const float* __restrict__ W2, const float* __restrict__ b2,
    float* __restrict__ out, uint32_t* __restrict__ ws)
{
  __shared__ __align__(16) float lA[2][64][68];   // [buf][k][m^swz], 34,816 B
  __shared__ __align__(16) float lB[2][32][68];   // [buf][n][k],     17,408 B
  __shared__ uint32_t lBits[64];                  // one spike word per row

  const int tid = threadIdx.x;
  const int tm  = tid & 15;      // m-group: rows tm*4 .. +3
  const int tn  = tid >> 4;      // n-group: cols tn*2 .. +1
  const int bid = blockIdx.x;

  uint32_t* spikes0  = ws + SPK0_OFF;
  uint32_t* spikes1  = ws + SPK1_OFF;
  float*    partials = (float*)(ws + PART_OFF);   // [NHELP][4096]
  uint32_t* flg   = ws + FLG_OFF;
  uint32_t* pflag = flg;            // [512] helper(bid)->owner: partials for t ready
  uint32_t* oflag = flg + 512;      // [512] owner(bid)->helper: consumed through t
  uint32_t* done0 = flg + 1024;     // [2][128] per m-half, target 64
  uint32_t* done1 = flg + 1280;     // [2][128]

  int group, kp, tl, m0, n0, K, hslot;
  const float *Wl, *bl;
  const uint32_t* spkIn; uint32_t* spkOut;
  uint32_t *dIn, *dOut;
  if (bid < 128) {          // L0: out 128x2048, K=1024, both chains in-block
    group=0; kp=0; tl=bid;
    m0=(tl>>6)*64; n0=(tl&63)*32; K=1024; Wl=W0; bl=b0;
    spkIn=nullptr; spkOut=spikes0; dIn=nullptr; dOut=done0 + (m0>>6)*128; hslot=-1;
  } else if (bid < 384) {   // L1: out 128x2048, K=2048, ksplit2
    group=1; int rel=bid-128; kp=rel&1; tl=rel>>1;
    m0=(tl>>6)*64; n0=(tl&63)*32; K=2048; Wl=W1; bl=b1;
    spkIn=spikes0; spkOut=spikes1;
    dIn=done0 + (m0>>6)*128; dOut=done1 + (m0>>6)*128; hslot=tl;
  } else {                  // L2: out 128x1024, K=2048, ksplit2
    group=2; int rel=bid-384; kp=rel&1; tl=rel>>1;
    m0=(tl>>5)*64; n0=(tl&31)*32; K=2048; Wl=W2; bl=b2;
    spkIn=spikes1; spkOut=nullptr;
    dIn=done1 + (m0>>6)*128; dOut=nullptr; hslot=128+tl;
  }
  const bool owner = (kp == 0);
  const int  K0    = kp * 1024;

  const float bias0 = bl[n0 + tn*2 + 0];
  const float bias1 = bl[n0 + tn*2 + 1];

  float vst[4][2];
  #pragma unroll
  for (int r = 0; r < 4; ++r) { vst[r][0] = 0.f; vst[r][1] = 0.f; }

  float4   ra[4];     // prefetched A chunk (group 0): 4 rows-of-16 x 4k
  float4   rb[2];     // prefetched B chunk: 2 rows-of-16 x 4k
  uint32_t rw[4];     // prefetched spike words (groups 1/2): 4 rows

  // staging decompositions (loop-invariant)
  const int s_sub = tid >> 4;       // 0..15
  const int s_kq  = tid & 15;       // float4 index along 64-k chunk

#define LOAD_REGS(KB) do {                                                     \
    const int kb_ = (KB);                                                      \
    _Pragma("unroll")                                                          \
    for (int it = 0; it < 2; ++it)                                             \
      rb[it] = *(const float4*)(Wl + (size_t)(n0 + s_sub + it*16)*K + kb_ + s_kq*4); \
    if (group == 0) {                                                          \
      _Pragma("unroll")                                                        \
      for (int it = 0; it < 4; ++it)                                           \
        ra[it] = *(const float4*)(x + ((size_t)(m0 + s_sub + it*16)*TT + t)*1024 + kb_ + s_kq*4); \
    } else {                                                                   \
      const size_t base_ = ((size_t)t*NB + m0 + s_kq*4)*64 + (kb_>>5) + (s_sub>>3); \
      _Pragma("unroll")                                                        \
      for (int j = 0; j < 4; ++j)                                              \
        rw[j] = __hip_atomic_load(&spkIn[base_ + (size_t)j*64],                \
                                  __ATOMIC_RELAXED, __HIP_MEMORY_SCOPE_AGENT); \
    }                                                                          \
  } while (0)

  for (int t = 0; t < TT; ++t) {
    if (dIn) {  // previous layer's spikes for this m-half must be complete
      if (tid == 0) wait_ge(&dIn[t], 64u);
      __syncthreads();
    }

    float acc2[2][4][2];   // two 512-k partial chains (p unrolled -> static idx)
    #pragma unroll
    for (int p = 0; p < 2; ++p)
      #pragma unroll
      for (int r = 0; r < 4; ++r) { acc2[p][r][0] = 0.f; acc2[p][r][1] = 0.f; }

    LOAD_REGS(K0);   // chunk 0 prologue

    #pragma unroll
    for (int p = 0; p < 2; ++p) {
      #pragma unroll 2
      for (int ch = 0; ch < 8; ++ch) {
        const int buf = ch & 1;
        float (*cA)[68] = lA[buf];
        float (*cB)[68] = lB[buf];

        // ---- write prefetched regs -> LDS[buf]
        #pragma unroll
        for (int it = 0; it < 2; ++it)
          *(float4*)&cB[s_sub + it*16][s_kq*4] = rb[it];
        if (group == 0) {
          const int k0 = s_kq*4, sw = fswz(k0);
          #pragma unroll
          for (int it = 0; it < 4; ++it) {
            const int col = (s_sub + it*16) ^ sw;
            cA[k0+0][col] = ra[it].x; cA[k0+1][col] = ra[it].y;
            cA[k0+2][col] = ra[it].z; cA[k0+3][col] = ra[it].w;
          }
        } else {    // expand 4 rows x 4 k from spike words
          #pragma unroll
          for (int i = 0; i < 4; ++i) {
            const int k  = s_sub*4 + i;        // local 0..63
            const int sh = k & 31;
            float4 f;
            f.x = ((rw[0] >> sh) & 1u) ? 1.0f : 0.0f;
            f.y = ((rw[1] >> sh) & 1u) ? 1.0f : 0.0f;
            f.z = ((rw[2] >> sh) & 1u) ? 1.0f : 0.0f;
            f.w = ((rw[3] >> sh) & 1u) ? 1.0f : 0.0f;
            *(float4*)&cA[k][(s_kq*4) ^ fswz(k)] = f;
          }
        }

        // ---- prefetch next chunk's globals (latency hides under FMA below)
        if (ch < 7)        LOAD_REGS(K0 + p*512 + (ch+1)*64);
        else if (p == 0)   LOAD_REGS(K0 + 512);

        // ---- raw barrier: wait LDS writes only; globals stay in flight
        __builtin_amdgcn_sched_barrier(0);
        asm volatile("s_waitcnt lgkmcnt(0)" ::: "memory");
        __builtin_amdgcn_s_barrier();
        __builtin_amdgcn_sched_barrier(0);

        // ---- FMA micro-kernel: 64 k x (4m x 2n), sequential ascending k
        #pragma unroll 4
        for (int k4 = 0; k4 < 16; ++k4) {
          const int kbase = k4*4;
          const int sw = fswz(kbase);           // constant over the 4 sub-ks
          const float* pa = &cA[kbase][(tm*4) ^ sw];
          const float4 b0 = *(const float4*)&cB[tn*2    ][kbase];
          const float4 b1 = *(const float4*)&cB[tn*2 + 1][kbase];
          #pragma unroll
          for (int u = 0; u < 4; ++u) {
            const float4 a  = *(const float4*)(pa + u*68);
            const float bv0 = (u==0) ? b0.x : (u==1) ? b0.y : (u==2) ? b0.z : b0.w;
            const float bv1 = (u==0) ? b1.x : (u==1) ? b1.y : (u==2) ? b1.z : b1.w;
            acc2[p][0][0] = __builtin_fmaf(a.x, bv0, acc2[p][0][0]);
            acc2[p][1][0] = __builtin_fmaf(a.y, bv0, acc2[p][1][0]);
            acc2[p][2][0] = __builtin_fmaf(a.z, bv0, acc2[p][2][0]);
            acc2[p][3][0] = __builtin_fmaf(a.w, bv0, acc2[p][3][0]);
            acc2[p][0][1] = __builtin_fmaf(a.x, bv1, acc2[p][0][1]);
            acc2[p][1][1] = __builtin_fmaf(a.y, bv1, acc2[p][1][1]);
            acc2[p][2][1] = __builtin_fmaf(a.z, bv1, acc2[p][2][1]);
            acc2[p][3][1] = __builtin_fmaf(a.w, bv1, acc2[p][3][1]);
          }
        }
        // no trailing barrier: next iter writes the OTHER buffer; the next
        // raw barrier orders reuse of this one (see dbuf safety analysis).
      }
    }

    if (!owner) {
      // single-buffered partials: wait until owner consumed t-1 before overwrite
      if (t >= 1) { if (tid == 0) wait_ge(&oflag[bid-1], (uint32_t)t); __syncthreads(); }
      uint64_t* pb = (uint64_t*)(partials + (size_t)hslot*4096) + tid*8;
      #pragma unroll
      for (int h = 0; h < 2; ++h)
        #pragma unroll
        for (int r = 0; r < 4; ++r) {
          union { float f[2]; uint64_t u; } cv;
          cv.f[0] = acc2[h][r][0]; cv.f[1] = acc2[h][r][1];
          __hip_atomic_store(&pb[h*4+r], cv.u, __ATOMIC_RELAXED, __HIP_MEMORY_SCOPE_AGENT);
        }
      __syncthreads();
      if (tid == 0) __hip_atomic_store(&pflag[bid], (uint32_t)(t+1), __ATOMIC_RELEASE, __HIP_MEMORY_SCOPE_AGENT);
      continue;
    }

    // owner: acc = (P0 + P1), then += P2, += P3 (ascending-k merge, DAG as R5)
    float acc[4][2];
    #pragma unroll
    for (int r = 0; r < 4; ++r) {
      acc[r][0] = __fadd_rn(acc2[0][r][0], acc2[1][r][0]);
      acc[r][1] = __fadd_rn(acc2[0][r][1], acc2[1][r][1]);
    }

    if (hslot >= 0) {   // L1/L2: fold in helper's P2 then P3
      if (tid == 0) wait_ge(&pflag[bid+1], (uint32_t)(t+1));
      __syncthreads();
      uint64_t* pb = (uint64_t*)(partials + (size_t)hslot*4096) + tid*8;
      #pragma unroll
      for (int h = 0; h < 2; ++h)
        #pragma unroll
        for (int r = 0; r < 4; ++r) {
          union { uint64_t u; float f[2]; } cv;
          cv.u = __hip_atomic_load(&pb[h*4+r], __ATOMIC_RELAXED, __HIP_MEMORY_SCOPE_AGENT);
          acc[r][0] = __fadd_rn(acc[r][0], cv.f[0]);
          acc[r][1] = __fadd_rn(acc[r][1], cv.f[1]);
        }
      __syncthreads();
      if (tid == 0) __hip_atomic_store(&oflag[bid], (uint32_t)(t+1), __ATOMIC_RELEASE, __HIP_MEMORY_SCOPE_AGENT);
    }

    if (group < 2) { if (tid < 64) lBits[tid] = 0; __syncthreads(); }

    // LIF: cur = acc + b (rn); v = 0.9*v + cur (mul+add rn, NO fma contraction);
    // spk = v > 1.0 strictly; v -= spk.
    float sv[4][2], vv8[4][2];
    #pragma unroll
    for (int r = 0; r < 4; ++r) {
      uint32_t msk = 0;
      #pragma unroll
      for (int c = 0; c < 2; ++c) {
        float cur = __fadd_rn(acc[r][c], c ? bias1 : bias0);
        float vv  = __fadd_rn(__fmul_rn(0.9f, vst[r][c]), cur);
        float s   = (vv > 1.0f) ? 1.0f : 0.0f;
        vv = __fsub_rn(vv, s);
        vst[r][c] = vv;
        sv[r][c] = s; vv8[r][c] = vv;
        msk |= (s != 0.f) ? (1u << (tn*2 + c)) : 0u;
      }
      if (group < 2 && msk) atomicOr(&lBits[tm*4 + r], msk);
    }

    if (group == 2) {
      #pragma unroll
      for (int r = 0; r < 4; ++r) {
        size_t o  = ((size_t)(m0 + tm*4 + r)*TT + t)*DD2 + n0 + tn*2;
        *(float2*)(out + o)  = make_float2(sv[r][0], sv[r][1]);
        size_t ov = (size_t)NB*TT*DD2 + o;
        *(float2*)(out + ov) = make_float2(vv8[r][0], vv8[r][1]);
      }
    } else {
      __syncthreads();
      if (tid < 64)
        __hip_atomic_store(&spkOut[((size_t)t*NB + m0 + tid)*64 + (n0>>5)],
                           lBits[tid], __ATOMIC_RELAXED, __HIP_MEMORY_SCOPE_AGENT);
      __syncthreads();
      if (tid == 0) __hip_atomic_fetch_add(&dOut[t], 1u, __ATOMIC_RELEASE, __HIP_MEMORY_SCOPE_AGENT);
    }
  }
#undef LOAD_REGS
}

extern "C" void kernel_launch(void* const* d_in, const int* in_sizes, int n_in,
                              void* d_out, int out_size, void* d_ws, size_t ws_size,
                              hipStream_t stream) {
  (void)in_sizes; (void)n_in; (void)out_size;
  float* outf = (float*)d_out;
  if (ws_size < WS_NEED_BYTES) {            // diagnostic: absmax ~41 => ws too small
    sentinel_kernel<<<1, 1, 0, stream>>>(outf);
    return;
  }
  const float* x  = (const float*)d_in[0];
  const float* W0 = (const float*)d_in[1];
  const float* b0 = (const float*)d_in[2];
  const float* W1 = (const float*)d_in[3];
  const float* b1 = (const float*)d_in[4];
  const float* W2 = (const float*)d_in[5];
  const float* b2 = (const float*)d_in[6];
  uint32_t* ws = (uint32_t*)d_ws;

  // zero flags (spikes/partials are write-before-read; flags gate everything)
  hipMemsetAsync(ws + FLG_OFF, 0, NFLG * sizeof(uint32_t), stream);

  snn_kernel<<<512, 256, 0, stream>>>(x, W0, b0, W1, b1, W2, b2, outf, ws);
}